// Round 10
// baseline (161.613 us; speedup 1.0000x reference)
//
#include <hip/hip_runtime.h>

#define E_TOTAL 800000
#define NN      50000
#define ND      64
#define ED      32
#define HD      128
#define OD      64
#define IND     160      // ED + 2*ND
#define MT      128      // edges per block
#define NTHREADS 512

typedef __attribute__((ext_vector_type(8))) short          short8;
typedef __attribute__((ext_vector_type(4))) float          f32x4;
typedef __attribute__((ext_vector_type(8))) unsigned short u16x8;
typedef __attribute__((ext_vector_type(4))) unsigned short u16x4;

__device__ __forceinline__ unsigned short f2bf(float f) {
  union { float f; unsigned u; } v; v.f = f;
  unsigned r = v.u + 0x7fffu + ((v.u >> 16) & 1u);   // RNE
  return (unsigned short)(r >> 16);
}

// async 16B/lane global->LDS: lds dest = wave-uniform base + lane*16,
// global src = per-lane address. Cannot be sunk by the compiler.
__device__ __forceinline__ void gload_lds16(const void* g, void* l) {
  __builtin_amdgcn_global_load_lds(
      (const __attribute__((address_space(1))) unsigned int*)g,
      (__attribute__((address_space(3))) unsigned int*)l, 16, 0, 0);
}

// ===================== LDS =====================
// X: 32 frags (wave w owns frags [w*4, w*4+4); H overlays them after L1).
// W1: only the FIRST 20 frags live in LDS; frags 20..39 are read per-use from
//     global (w1p stays L2-hot at 40KB). LDS = 32K + 20K = 53,248 B -> 3 blk/CU.
#define X_FRAGS      32
#define W1_LDS_FRAGS 20
#define SMEM_U16 ((X_FRAGS + W1_LDS_FRAGS) * 512)
#define SMEM_BYTES (SMEM_U16 * 2)           // 53248

// ---------- prepass: f32 -> bf16 node table ----------
__global__ void cvt_nodes(const float* __restrict__ in, unsigned short* __restrict__ out, int n4) {
  int i = blockIdx.x * blockDim.x + threadIdx.x;
  const int stride = gridDim.x * blockDim.x;
  for (; i < n4; i += stride) {
    float4 v = ((const float4*)in)[i];
    u16x4 o = { f2bf(v.x), f2bf(v.y), f2bf(v.z), f2bf(v.w) };
    ((u16x4*)out)[i] = o;
  }
}

// ---------- prepass: pack W1 into B-fragment order ----------
__global__ void pack_w1(const float* __restrict__ w, unsigned short* __restrict__ out) {
  int i = blockIdx.x * blockDim.x + threadIdx.x;
  if (i >= HD * IND) return;
  int j = i & 7, l = (i >> 3) & 63, f = i >> 9;   // f in [0,40)
  int ks = f >> 3, t = f & 7;
  int k = ks * 32 + (l >> 4) * 8 + j;
  int n = t * 16 + (l & 15);
  out[i] = f2bf(w[k * HD + n]);
}

// ---------- prepass: pack W2 into B-fragment order ----------
__global__ void pack_w2(const float* __restrict__ w, unsigned short* __restrict__ out) {
  int i = blockIdx.x * blockDim.x + threadIdx.x;
  if (i >= OD * HD) return;
  int j = i & 7, l = (i >> 3) & 63, f = i >> 9;   // f in [0,16)
  int ks = f >> 2, t = f & 3;
  int k = ks * 32 + (l >> 4) * 8 + j;
  int n = t * 16 + (l & 15);
  out[i] = f2bf(w[k * OD + n]);
}

// ---------- main fused kernel: async-staged, one barrier, 3 blocks/CU ----------
__global__ __launch_bounds__(NTHREADS, 6)
void edge_mlp(const int* __restrict__ eidx,
              const float* __restrict__ ef,
              const unsigned short* __restrict__ nbf,
              const unsigned short* __restrict__ w1p,
              const unsigned short* __restrict__ w2p,
              const float* __restrict__ b1,
              const float* __restrict__ b2,
              float* __restrict__ out)
{
  extern __shared__ unsigned short sm[];
  unsigned short* Xs = sm;                  // 32 frags (H overlays after L1)
  unsigned short* W1 = sm + X_FRAGS * 512;  // 20 frags (f = 0..19)

  const int tid  = threadIdx.x;
  const int wid  = tid >> 6;
  const int lane = tid & 63;
  const int lq   = lane >> 4;
  const int lr   = lane & 15;
  const long e   = (long)blockIdx.x * MT + wid * 16 + lr;   // this lane's edge

  // ---- 1) index loads (head of the dependent chain)
  int si = eidx[e];
  int ti = eidx[E_TOTAL + e];

  // ---- 2) W1 staging: frags 0..19, waves 0..4 stage 4 frags each
  if (wid < 5) {
    #pragma unroll
    for (int c = 0; c < 4; ++c) {
      const int f = wid * 4 + c;
      gload_lds16(w1p + f * 512 + lane * 8, W1 + f * 512);
    }
  }

  // ---- 3) edge features (register path; ks=0 A-frag, converted later)
  const float4 e0v = *(const float4*)(ef + e * ED + lq * 8);
  const float4 e1v = *(const float4*)(ef + e * ED + lq * 8 + 4);

  // ---- 4) biases
  float b1v[8];
  #pragma unroll
  for (int t = 0; t < 8; ++t) b1v[t] = b1[t * 16 + lr];
  float b2v[4];
  #pragma unroll
  for (int t = 0; t < 4; ++t) b2v[t] = b2[t * 16 + lr];

  // ---- 5) node gathers: 4 async frag-copies per wave, per-lane src addresses
  si = si < 0 ? 0 : (si >= NN ? NN - 1 : si);
  ti = ti < 0 ? 0 : (ti >= NN ? NN - 1 : ti);
  const unsigned short* sr = nbf + (long)si * ND;
  const unsigned short* tr = nbf + (long)ti * ND;
  unsigned short* xbase = Xs + (wid * 4) * 512;
  gload_lds16(sr + lq * 8,      xbase);            // frag wid*4+0: src k[0,32)
  gload_lds16(sr + 32 + lq * 8, xbase + 512);      // frag wid*4+1: src k[32,64)
  gload_lds16(tr + lq * 8,      xbase + 1024);     // frag wid*4+2: tgt k[0,32)
  gload_lds16(tr + 32 + lq * 8, xbase + 1536);     // frag wid*4+3: tgt k[32,64)

  // ---- 6) single drain + single barrier (X own-wave + W1 shared)
  asm volatile("s_waitcnt vmcnt(0)" ::: "memory");
  __builtin_amdgcn_s_barrier();
  __builtin_amdgcn_sched_barrier(0);

  // ---- A-frag ks=0 from edge features
  short8 aef;
  aef[0] = (short)f2bf(e0v.x); aef[1] = (short)f2bf(e0v.y);
  aef[2] = (short)f2bf(e0v.z); aef[3] = (short)f2bf(e0v.w);
  aef[4] = (short)f2bf(e1v.x); aef[5] = (short)f2bf(e1v.y);
  aef[6] = (short)f2bf(e1v.z); aef[7] = (short)f2bf(e1v.w);

  // ---- layer 1: H[128x128] = X @ W1  (B: frag<20 from LDS, else global)
  f32x4 acc[8];
  #pragma unroll
  for (int t = 0; t < 8; ++t) acc[t] = (f32x4)0.0f;

  #pragma unroll
  for (int kk = 0; kk < 4; ++kk) {                    // ks = 1..4
    const short8 a = *(const short8*)(xbase + kk * 512 + lane * 8);
    #pragma unroll
    for (int t = 0; t < 8; ++t) {
      const int f = (kk + 1) * 8 + t;
      const short8 b = (f < W1_LDS_FRAGS)
        ? *(const short8*)(W1 + f * 512 + lane * 8)
        : *(const short8*)(w1p + f * 512 + lane * 8);
      acc[t] = __builtin_amdgcn_mfma_f32_16x16x32_bf16(a, b, acc[t], 0, 0, 0);
    }
  }
  #pragma unroll
  for (int t = 0; t < 8; ++t) {                       // ks = 0 (edge feats, LDS)
    const short8 b = *(const short8*)(W1 + t * 512 + lane * 8);
    acc[t] = __builtin_amdgcn_mfma_f32_16x16x32_bf16(aef, b, acc[t], 0, 0, 0);
  }

  // ---- relu + bias -> H A-frags overlaying own X frags (wave-private)
  #pragma unroll
  for (int t = 0; t < 8; ++t) {
    #pragma unroll
    for (int r = 0; r < 4; ++r) {
      float h = acc[t][r] + b1v[t];
      h = h > 0.0f ? h : 0.0f;
      const int k    = t * 16 + lr;
      const int frag = (k >> 5);
      const int l2   = (((k >> 3) & 3) << 4) + lq * 4 + r;
      xbase[frag * 512 + l2 * 8 + (k & 7)] = f2bf(h);
    }
  }

  // ---- read back own H A-frags
  short8 a2[4];
  #pragma unroll
  for (int ks = 0; ks < 4; ++ks)
    a2[ks] = *(const short8*)(xbase + ks * 512 + lane * 8);

  // ---- layer 2: OUT[128x64] = H @ W2 (B frags from global, L1/L2-hot)
  f32x4 acc2[4];
  #pragma unroll
  for (int t = 0; t < 4; ++t) acc2[t] = (f32x4)0.0f;
  #pragma unroll
  for (int t = 0; t < 4; ++t) {
    #pragma unroll
    for (int ks = 0; ks < 4; ++ks) {
      const short8 b = *(const short8*)(w2p + ((ks * 4 + t) * 64 + lane) * 8);
      acc2[t] = __builtin_amdgcn_mfma_f32_16x16x32_bf16(a2[ks], b, acc2[t], 0, 0, 0);
    }
  }

  // ---- epilogue: bias + f32 store
  const long mbase = (long)blockIdx.x * MT + wid * 16 + lq * 4;
  #pragma unroll
  for (int t = 0; t < 4; ++t) {
    #pragma unroll
    for (int r = 0; r < 4; ++r) {
      out[(mbase + r) * OD + t * 16 + lr] = acc2[t][r] + b2v[t];
    }
  }
}

extern "C" void kernel_launch(void* const* d_in, const int* in_sizes, int n_in,
                              void* d_out, int out_size, void* d_ws, size_t ws_size,
                              hipStream_t stream) {
  const int*   eidx = (const int*)d_in[0];      // (2, E) int32
  const float* nf   = (const float*)d_in[1];    // (NN, 64)
  const float* ef   = (const float*)d_in[2];    // (E, 32)
  const float* w1   = (const float*)d_in[3];    // (160, 128)
  const float* b1   = (const float*)d_in[4];    // (128,)
  const float* w2   = (const float*)d_in[5];    // (128, 64)
  const float* b2   = (const float*)d_in[6];    // (64,)
  float*       out  = (float*)d_out;            // (E, 64)

  unsigned short* nbf = (unsigned short*)d_ws;            // NN*ND
  unsigned short* w1p = nbf + (long)NN * ND;              // HD*IND
  unsigned short* w2p = w1p + (long)HD * IND;             // OD*HD

  cvt_nodes<<<1024, 256, 0, stream>>>(nf, nbf, (NN * ND) / 4);
  pack_w1<<<(HD * IND + 255) / 256, 256, 0, stream>>>(w1, w1p);
  pack_w2<<<(OD * HD + 255) / 256, 256, 0, stream>>>(w2, w2p);

  hipFuncSetAttribute((const void*)edge_mlp,
                      hipFuncAttributeMaxDynamicSharedMemorySize, SMEM_BYTES);
  edge_mlp<<<E_TOTAL / MT, NTHREADS, SMEM_BYTES, stream>>>(
      eidx, ef, nbf, w1p, w2p, b1, b2, out);
}